// Round 1
// baseline (326.022 us; speedup 1.0000x reference)
//
#include <hip/hip_runtime.h>
#include <math.h>

#define L_SEQ 8192
#define B_BATCH 8
#define D_DIM 256
#define BL (B_BATCH * L_SEQ)
#define EPS_F 1.1920929e-07f

// ws layout (bytes):
//   [0,       262144)  M fp32 256x256
//   [262144,  327680)  hard  uint8  BL
//   [327680,  589824)  starts int32 BL
//   [589824,  589856)  n_b   int32  8
//   [589856,  589888)  len   int32  8

// ---------------------------------------------------------------- K1: M = Wq^T * Wk
__global__ void k_matM(const float* __restrict__ Wq, const float* __restrict__ Wk,
                       float* __restrict__ M) {
    __shared__ float Aq[16][17];
    __shared__ float Ak[16][17];
    const int tx = threadIdx.x, ty = threadIdx.y;
    const int d  = blockIdx.y * 16 + ty;   // row of M
    const int dp = blockIdx.x * 16 + tx;   // col of M
    float acc = 0.f;
    for (int e0 = 0; e0 < 256; e0 += 16) {
        Aq[ty][tx] = Wq[(e0 + ty) * 256 + blockIdx.y * 16 + tx];
        Ak[ty][tx] = Wk[(e0 + ty) * 256 + blockIdx.x * 16 + tx];
        __syncthreads();
#pragma unroll
        for (int i = 0; i < 16; ++i) acc += Aq[i][ty] * Ak[i][tx];
        __syncthreads();
    }
    M[d * 256 + dp] = acc;
}

// ------------------------------------------- K3: normalize + V=hn*M + cos + hard bit
// Block handles outputs t in [T0, T0+32). Needs hn rows T0-1 .. T0+31 (33 rows).
// Register tile: 4 tokens x 8 cols per thread (32 col-groups x 8 token-groups).
__global__ __launch_bounds__(256) void k_coshard(
    const float* __restrict__ hidden, const float* __restrict__ M,
    const float* __restrict__ noise, unsigned char* __restrict__ hard) {
    __shared__ __attribute__((aligned(16))) float hn[33 * 260];
    __shared__ __attribute__((aligned(16))) float Ms[16 * 260];

    const int tid  = threadIdx.x;
    const int lane = tid & 63;
    const int w    = tid >> 6;
    const int T0   = blockIdx.x * 32;

    // stage + normalize 33 rows of hidden into LDS (row i <-> global token T0-1+i)
    for (int i = w; i < 33; i += 4) {
        int r = T0 - 1 + i;
        r = r < 0 ? 0 : r;
        const float4 v = ((const float4*)hidden)[r * 64 + lane];
        float ss = v.x * v.x + v.y * v.y + v.z * v.z + v.w * v.w;
#pragma unroll
        for (int m = 32; m >= 1; m >>= 1) ss += __shfl_xor(ss, m);
        const float den = fmaxf(sqrtf(ss), 1e-12f);
        float4 h4;
        h4.x = v.x / den; h4.y = v.y / den; h4.z = v.z / den; h4.w = v.w / den;
        *(float4*)&hn[i * 260 + lane * 4] = h4;
    }

    const int cg  = tid & 31;        // col-group: cols [8cg, 8cg+8)
    const int tg  = tid >> 5;        // token-group: tile rows [4tg, 4tg+4)
    const int tg4 = tg * 4;
    const int cg8 = cg * 8;

    float acc[4][8];
#pragma unroll
    for (int r = 0; r < 4; ++r)
#pragma unroll
        for (int i = 0; i < 8; ++i) acc[r][i] = 0.f;

    for (int ks = 0; ks < 256; ks += 16) {
        __syncthreads();
        // stage M strip rows [ks, ks+16) : 1024 float4, 4 per thread
#pragma unroll
        for (int n = 0; n < 4; ++n) {
            const int f   = n * 256 + tid;   // float4 index in strip
            const int row = f >> 6, c4 = f & 63;
            *(float4*)&Ms[row * 260 + c4 * 4] = ((const float4*)M)[(ks + row) * 64 + c4];
        }
        __syncthreads();
#pragma unroll
        for (int k = 0; k < 16; ++k) {
            const int kk = ks + k;
            float a[4];
#pragma unroll
            for (int r = 0; r < 4; ++r) a[r] = hn[(tg4 + r) * 260 + kk];
            const float4 b0 = *(const float4*)&Ms[k * 260 + cg8];
            const float4 b1 = *(const float4*)&Ms[k * 260 + cg8 + 4];
            float bb[8] = {b0.x, b0.y, b0.z, b0.w, b1.x, b1.y, b1.z, b1.w};
#pragma unroll
            for (int r = 0; r < 4; ++r)
#pragma unroll
                for (int i = 0; i < 8; ++i) acc[r][i] += a[r] * bb[i];
        }
    }

    // epilogue: cos(t=T0+j) = V[j] . hn[j+1], then hard decision
    float part[4];
#pragma unroll
    for (int r = 0; r < 4; ++r) {
        part[r] = 0.f;
#pragma unroll
        for (int i = 0; i < 8; ++i) part[r] += acc[r][i] * hn[(tg4 + r + 1) * 260 + cg8 + i];
#pragma unroll
        for (int m = 16; m >= 1; m >>= 1) part[r] += __shfl_xor(part[r], m);
    }
    if (cg == 0) {
#pragma unroll
        for (int r = 0; r < 4; ++r) {
            const int j = tg4 + r;
            const int t = T0 + j;
            const int l = t & (L_SEQ - 1);
            float p;
            if (l == 0) {
                p = 1.0f;
            } else {
                p = (1.0f - part[r]) * 0.5f;
                p = fminf(fmaxf(p, 0.0f), 1.0f);
            }
            p = fminf(fmaxf(p, EPS_F), 1.0f - EPS_F);
            float u = noise[t];
            u = fminf(fmaxf(u, EPS_F), 1.0f - EPS_F);
            const float z = ((logf(p) - log1pf(-p)) + logf(u)) - log1pf(-u);
            hard[t] = (z > 0.0f) ? (unsigned char)1 : (unsigned char)0;
        }
    }
}

// ---------------------- K4: per-row length, forced boundary, scan -> starts, n_b, mask
__global__ void k_scan(const float* __restrict__ mask, const unsigned char* __restrict__ hard,
                       int* __restrict__ starts, int* __restrict__ nb_arr,
                       int* __restrict__ len_arr, float* __restrict__ out_short) {
    __shared__ int sc[256];
    __shared__ int s_len;
    const int b = blockIdx.x, tid = threadIdx.x;
    const int base = b * L_SEQ;

    // row length = sum(mask) (contiguous prefix of ones)
    int cnt = 0;
    for (int i = tid; i < L_SEQ; i += 256) cnt += (mask[base + i] != 0.0f) ? 1 : 0;
    sc[tid] = cnt;
    __syncthreads();
    for (int ofs = 128; ofs > 0; ofs >>= 1) {
        if (tid < ofs) sc[tid] += sc[tid + ofs];
        __syncthreads();
    }
    if (tid == 0) s_len = sc[0];
    __syncthreads();
    const int len = s_len;

    // adjusted hard bits for this thread's contiguous chunk [32*tid, 32*tid+32)
    const int i0 = tid * 32;
    unsigned int bits = 0;
    int c = 0;
#pragma unroll
    for (int j = 0; j < 32; ++j) {
        const int i = i0 + j;
        int h = (i < len) ? (int)hard[base + i] : 0;
        if (len < L_SEQ && i == len - 1) h = 1;  // forced boundary at last real token
        bits |= (unsigned int)h << j;
        c += h;
    }
    __syncthreads();
    sc[tid] = c;
    __syncthreads();
    // inclusive Hillis-Steele scan over 256 thread counts
    for (int ofs = 1; ofs < 256; ofs <<= 1) {
        const int v = (tid >= ofs) ? sc[tid - ofs] : 0;
        __syncthreads();
        sc[tid] += v;
        __syncthreads();
    }
    const int off = sc[tid] - c;
    const int nb = sc[255];

    int run = off;
#pragma unroll
    for (int j = 0; j < 32; ++j)
        if ((bits >> j) & 1u) { starts[base + run] = i0 + j; ++run; }

    if (tid == 0) { nb_arr[b] = nb; len_arr[b] = len; }

    for (int i = tid; i < L_SEQ; i += 256) out_short[base + i] = (i < nb) ? 1.0f : 0.0f;
}

// --------------------------------------------- K5: one wave per segment, mean-pool
__global__ __launch_bounds__(256) void k_pool(
    const float* __restrict__ hidden, const int* __restrict__ starts,
    const int* __restrict__ nb_arr, const int* __restrict__ len_arr,
    float* __restrict__ pooled) {
    const int tid  = threadIdx.x;
    const int lane = tid & 63;
    const int wid  = blockIdx.x * 4 + (tid >> 6);
    const int b    = wid >> 13;       // / 8192
    const int s    = wid & (L_SEQ - 1);
    const int nb   = nb_arr[b];

    float4 res = {0.f, 0.f, 0.f, 0.f};
    if (s < nb) {
        const int start = (s == 0) ? 0 : starts[b * L_SEQ + s];
        const int end   = (s + 1 < nb) ? starts[b * L_SEQ + s + 1] : len_arr[b];
        float4 acc = {0.f, 0.f, 0.f, 0.f};
        for (int t = start; t < end; ++t) {
            const float4 v = ((const float4*)hidden)[(b * L_SEQ + t) * 64 + lane];
            acc.x += v.x; acc.y += v.y; acc.z += v.z; acc.w += v.w;
        }
        const float cntf = (float)(end - start);
        res.x = acc.x / cntf; res.y = acc.y / cntf; res.z = acc.z / cntf; res.w = acc.w / cntf;
    }
    ((float4*)pooled)[(size_t)wid * 64 + lane] = res;
}

// ---------------------------------------------------- K6: scalars (loss via lgamma)
__global__ void k_final(const int* __restrict__ nb_arr, const int* __restrict__ len_arr,
                        float* __restrict__ out_scal) {
    if (threadIdx.x == 0) {
        int nb = 0, ln = 0;
        for (int b = 0; b < B_BATCH; ++b) { nb += nb_arr[b]; ln += len_arr[b]; }
        const double k = (double)nb, n = (double)ln;
        const double logp = lgamma(n + 1.0) - lgamma(k + 1.0) - lgamma(n - k + 1.0)
                            + k * log(0.2) + (n - k) * log(0.8);
        const double loss = -logp / n;
        out_scal[0] = (float)loss;
        out_scal[1] = (float)nb;
        out_scal[2] = (float)ln;
    }
}

extern "C" void kernel_launch(void* const* d_in, const int* in_sizes, int n_in,
                              void* d_out, int out_size, void* d_ws, size_t ws_size,
                              hipStream_t stream) {
    const float* hidden = (const float*)d_in[0];
    const float* Wq     = (const float*)d_in[1];
    const float* Wk     = (const float*)d_in[2];
    const float* noise  = (const float*)d_in[3];
    const float* mask   = (const float*)d_in[4];
    float* out = (float*)d_out;
    char* ws = (char*)d_ws;

    float*         M      = (float*)(ws);
    unsigned char* hard   = (unsigned char*)(ws + 262144);
    int*           starts = (int*)(ws + 327680);
    int*           nb_arr = (int*)(ws + 589824);
    int*           len_arr= (int*)(ws + 589856);

    float* pooled = out;
    float* scal   = out + (size_t)BL * D_DIM;
    float* shortm = scal + 3;

    k_matM  <<<dim3(16, 16), dim3(16, 16), 0, stream>>>(Wq, Wk, M);
    k_coshard<<<BL / 32, 256, 0, stream>>>(hidden, M, noise, hard);
    k_scan  <<<B_BATCH, 256, 0, stream>>>(mask, hard, starts, nb_arr, len_arr, shortm);
    k_pool  <<<BL / 4, 256, 0, stream>>>(hidden, starts, nb_arr, len_arr, pooled);
    k_final <<<1, 64, 0, stream>>>(nb_arr, len_arr, scal);
}

// Round 2
// 287.343 us; speedup vs baseline: 1.1346x; 1.1346x over previous
//
#include <hip/hip_runtime.h>
#include <math.h>

#define L_SEQ 8192
#define B_BATCH 8
#define D_DIM 256
#define BL (B_BATCH * L_SEQ)
#define EPS_F 1.1920929e-07f

// ws layout (bytes):
//   [0,       262144)  M fp32 256x256
//   [262144,  327680)  hard  uint8  BL
//   [327680,  589824)  starts int32 BL
//   [589824,  589856)  n_b   int32  8
//   [589856,  589888)  len   int32  8

// ---------------------------------------------------------------- K1: M = Wq^T * Wk
__global__ void k_matM(const float* __restrict__ Wq, const float* __restrict__ Wk,
                       float* __restrict__ M) {
    __shared__ float Aq[16][17];
    __shared__ float Ak[16][17];
    const int tx = threadIdx.x, ty = threadIdx.y;
    const int d  = blockIdx.y * 16 + ty;   // row of M
    const int dp = blockIdx.x * 16 + tx;   // col of M
    float acc = 0.f;
    for (int e0 = 0; e0 < 256; e0 += 16) {
        Aq[ty][tx] = Wq[(e0 + ty) * 256 + blockIdx.y * 16 + tx];
        Ak[ty][tx] = Wk[(e0 + ty) * 256 + blockIdx.x * 16 + tx];
        __syncthreads();
#pragma unroll
        for (int i = 0; i < 16; ++i) acc += Aq[i][ty] * Ak[i][tx];
        __syncthreads();
    }
    M[d * 256 + dp] = acc;
}

// ------------------------------------------- K3: normalize + V=hn*M + cos + hard bit
// Block = 256 thr = 4 waves, 32 output tokens [T0, T0+32). LDS rows i <-> token T0-1+i.
// Wave w owns tokens 8w..8w+8; lane = column-quad (cols 4*lane..4*lane+4).
// Inner loop: A = LDS broadcast b128 (conflict-free), B = M row from global
// (full-wave coalesced 1 KB, L1/L2 resident). No barriers in the K-loop.
__global__ __launch_bounds__(256) void k_coshard(
    const float* __restrict__ hidden, const float* __restrict__ M,
    const float* __restrict__ noise, unsigned char* __restrict__ hard) {
    __shared__ __attribute__((aligned(16))) float hn[33 * 260];

    const int tid  = threadIdx.x;
    const int lane = tid & 63;
    const int w    = tid >> 6;
    const int T0   = blockIdx.x * 32;

    // stage + normalize 33 rows of hidden into LDS
    for (int i = w; i < 33; i += 4) {
        int r = T0 - 1 + i;
        r = r < 0 ? 0 : r;
        const float4 v = ((const float4*)hidden)[r * 64 + lane];
        float ss = v.x * v.x + v.y * v.y + v.z * v.z + v.w * v.w;
#pragma unroll
        for (int m = 32; m >= 1; m >>= 1) ss += __shfl_xor(ss, m);
        const float den = fmaxf(sqrtf(ss), 1e-12f);
        float4 h4;
        h4.x = v.x / den; h4.y = v.y / den; h4.z = v.z / den; h4.w = v.w / den;
        *(float4*)&hn[i * 260 + lane * 4] = h4;
    }
    __syncthreads();

    const int w8 = w * 8;
    const float4* __restrict__ Mf4 = (const float4*)M;

    float acc[8][4];
#pragma unroll
    for (int r = 0; r < 8; ++r)
#pragma unroll
        for (int i = 0; i < 4; ++i) acc[r][i] = 0.f;

#pragma unroll 2
    for (int k4 = 0; k4 < 64; ++k4) {
        // B: 4 rows of M, each read full-wave coalesced
        float4 m0 = Mf4[(k4 * 4 + 0) * 64 + lane];
        float4 m1 = Mf4[(k4 * 4 + 1) * 64 + lane];
        float4 m2 = Mf4[(k4 * 4 + 2) * 64 + lane];
        float4 m3 = Mf4[(k4 * 4 + 3) * 64 + lane];
        // A: 8 token rows, 4 k-values each, LDS broadcast
        float4 a8[8];
#pragma unroll
        for (int r = 0; r < 8; ++r)
            a8[r] = *(const float4*)&hn[(w8 + r) * 260 + k4 * 4];
#pragma unroll
        for (int r = 0; r < 8; ++r) {
            acc[r][0] += a8[r].x * m0.x; acc[r][1] += a8[r].x * m0.y;
            acc[r][2] += a8[r].x * m0.z; acc[r][3] += a8[r].x * m0.w;
            acc[r][0] += a8[r].y * m1.x; acc[r][1] += a8[r].y * m1.y;
            acc[r][2] += a8[r].y * m1.z; acc[r][3] += a8[r].y * m1.w;
            acc[r][0] += a8[r].z * m2.x; acc[r][1] += a8[r].z * m2.y;
            acc[r][2] += a8[r].z * m2.z; acc[r][3] += a8[r].z * m2.w;
            acc[r][0] += a8[r].w * m3.x; acc[r][1] += a8[r].w * m3.y;
            acc[r][2] += a8[r].w * m3.z; acc[r][3] += a8[r].w * m3.w;
        }
    }

    // epilogue: cos(token t=T0+w8+r) = V[row w8+r] . hn[row w8+r+1]
    float part[8];
#pragma unroll
    for (int r = 0; r < 8; ++r) {
        const float4 h0 = *(const float4*)&hn[(w8 + r + 1) * 260 + lane * 4];
        part[r] = acc[r][0] * h0.x + acc[r][1] * h0.y + acc[r][2] * h0.z + acc[r][3] * h0.w;
#pragma unroll
        for (int m = 32; m >= 1; m >>= 1) part[r] += __shfl_xor(part[r], m);
    }
    if (lane == 0) {
#pragma unroll
        for (int r = 0; r < 8; ++r) {
            const int t = T0 + w8 + r;
            const int l = t & (L_SEQ - 1);
            float p;
            if (l == 0) {
                p = 1.0f;
            } else {
                p = (1.0f - part[r]) * 0.5f;
                p = fminf(fmaxf(p, 0.0f), 1.0f);
            }
            p = fminf(fmaxf(p, EPS_F), 1.0f - EPS_F);
            float u = noise[t];
            u = fminf(fmaxf(u, EPS_F), 1.0f - EPS_F);
            const float z = ((logf(p) - log1pf(-p)) + logf(u)) - log1pf(-u);
            hard[t] = (z > 0.0f) ? (unsigned char)1 : (unsigned char)0;
        }
    }
}

// ---------------------- K4: per-row length, forced boundary, scan -> starts, n_b, mask
__global__ void k_scan(const float* __restrict__ mask, const unsigned char* __restrict__ hard,
                       int* __restrict__ starts, int* __restrict__ nb_arr,
                       int* __restrict__ len_arr, float* __restrict__ out_short) {
    __shared__ int sc[256];
    __shared__ int s_len;
    const int b = blockIdx.x, tid = threadIdx.x;
    const int base = b * L_SEQ;

    // row length = sum(mask) (contiguous prefix of ones)
    int cnt = 0;
    for (int i = tid; i < L_SEQ; i += 256) cnt += (mask[base + i] != 0.0f) ? 1 : 0;
    sc[tid] = cnt;
    __syncthreads();
    for (int ofs = 128; ofs > 0; ofs >>= 1) {
        if (tid < ofs) sc[tid] += sc[tid + ofs];
        __syncthreads();
    }
    if (tid == 0) s_len = sc[0];
    __syncthreads();
    const int len = s_len;

    // adjusted hard bits for this thread's contiguous chunk [32*tid, 32*tid+32)
    const int i0 = tid * 32;
    unsigned int bits = 0;
    int c = 0;
#pragma unroll
    for (int j = 0; j < 32; ++j) {
        const int i = i0 + j;
        int h = (i < len) ? (int)hard[base + i] : 0;
        if (len < L_SEQ && i == len - 1) h = 1;  // forced boundary at last real token
        bits |= (unsigned int)h << j;
        c += h;
    }
    __syncthreads();
    sc[tid] = c;
    __syncthreads();
    // inclusive Hillis-Steele scan over 256 thread counts
    for (int ofs = 1; ofs < 256; ofs <<= 1) {
        const int v = (tid >= ofs) ? sc[tid - ofs] : 0;
        __syncthreads();
        sc[tid] += v;
        __syncthreads();
    }
    const int off = sc[tid] - c;
    const int nb = sc[255];

    int run = off;
#pragma unroll
    for (int j = 0; j < 32; ++j)
        if ((bits >> j) & 1u) { starts[base + run] = i0 + j; ++run; }

    if (tid == 0) { nb_arr[b] = nb; len_arr[b] = len; }

    for (int i = tid; i < L_SEQ; i += 256) out_short[base + i] = (i < nb) ? 1.0f : 0.0f;
}

// --------------------------------------------- K5: one wave per segment, mean-pool
__global__ __launch_bounds__(256) void k_pool(
    const float* __restrict__ hidden, const int* __restrict__ starts,
    const int* __restrict__ nb_arr, const int* __restrict__ len_arr,
    float* __restrict__ pooled) {
    const int tid  = threadIdx.x;
    const int lane = tid & 63;
    const int wid  = blockIdx.x * 4 + (tid >> 6);
    const int b    = wid >> 13;       // / 8192
    const int s    = wid & (L_SEQ - 1);
    const int nb   = nb_arr[b];

    float4 res = {0.f, 0.f, 0.f, 0.f};
    if (s < nb) {
        const int start = (s == 0) ? 0 : starts[b * L_SEQ + s];
        const int end   = (s + 1 < nb) ? starts[b * L_SEQ + s + 1] : len_arr[b];
        float4 acc = {0.f, 0.f, 0.f, 0.f};
        for (int t = start; t < end; ++t) {
            const float4 v = ((const float4*)hidden)[(b * L_SEQ + t) * 64 + lane];
            acc.x += v.x; acc.y += v.y; acc.z += v.z; acc.w += v.w;
        }
        const float cntf = (float)(end - start);
        res.x = acc.x / cntf; res.y = acc.y / cntf; res.z = acc.z / cntf; res.w = acc.w / cntf;
    }
    ((float4*)pooled)[(size_t)wid * 64 + lane] = res;
}

// ---------------------------------------------------- K6: scalars (loss via lgamma)
__global__ void k_final(const int* __restrict__ nb_arr, const int* __restrict__ len_arr,
                        float* __restrict__ out_scal) {
    if (threadIdx.x == 0) {
        int nb = 0, ln = 0;
        for (int b = 0; b < B_BATCH; ++b) { nb += nb_arr[b]; ln += len_arr[b]; }
        const double k = (double)nb, n = (double)ln;
        const double logp = lgamma(n + 1.0) - lgamma(k + 1.0) - lgamma(n - k + 1.0)
                            + k * log(0.2) + (n - k) * log(0.8);
        const double loss = -logp / n;
        out_scal[0] = (float)loss;
        out_scal[1] = (float)nb;
        out_scal[2] = (float)ln;
    }
}

extern "C" void kernel_launch(void* const* d_in, const int* in_sizes, int n_in,
                              void* d_out, int out_size, void* d_ws, size_t ws_size,
                              hipStream_t stream) {
    const float* hidden = (const float*)d_in[0];
    const float* Wq     = (const float*)d_in[1];
    const float* Wk     = (const float*)d_in[2];
    const float* noise  = (const float*)d_in[3];
    const float* mask   = (const float*)d_in[4];
    float* out = (float*)d_out;
    char* ws = (char*)d_ws;

    float*         M      = (float*)(ws);
    unsigned char* hard   = (unsigned char*)(ws + 262144);
    int*           starts = (int*)(ws + 327680);
    int*           nb_arr = (int*)(ws + 589824);
    int*           len_arr= (int*)(ws + 589856);

    float* pooled = out;
    float* scal   = out + (size_t)BL * D_DIM;
    float* shortm = scal + 3;

    k_matM  <<<dim3(16, 16), dim3(16, 16), 0, stream>>>(Wq, Wk, M);
    k_coshard<<<BL / 32, 256, 0, stream>>>(hidden, M, noise, hard);
    k_scan  <<<B_BATCH, 256, 0, stream>>>(mask, hard, starts, nb_arr, len_arr, shortm);
    k_pool  <<<BL / 4, 256, 0, stream>>>(hidden, starts, nb_arr, len_arr, pooled);
    k_final <<<1, 64, 0, stream>>>(nb_arr, len_arr, scal);
}